// Round 2
// baseline (2799.452 us; speedup 1.0000x reference)
//
#include <hip/hip_runtime.h>
#include <math.h>

#define NFFT    2048
#define HOP     960
#define NMELS   64
#define NDIR    2304
#define BATCH   8
#define NSAMP   960000
#define NF      1025
#define FP      1040
#define TFRAMES 1001
#define BK      16
#define LDT     68

#define SZF ((size_t)BATCH * TFRAMES * FP)
#define SZW ((size_t)NDIR * FP)

// ---------------------------------------------------------------- pad copy
__global__ __launch_bounds__(256) void pad_copy_k(const float* __restrict__ src,
                                                  float* __restrict__ dst, int rows) {
  int total = rows * FP;
  for (int idx = blockIdx.x * 256 + threadIdx.x; idx < total; idx += gridDim.x * 256) {
    int r = idx / FP, c = idx - r * FP;
    dst[idx] = (c < NF) ? src[r * NF + c] : 0.0f;
  }
}

// ---------------------------------------------------------------- STFT + features
// One block per (b,t). Two-for-one: z = xL + i*xR, one 2048-pt Stockham FFT,
// Hermitian split -> XL, XR; writes powL, powR, csd_r, csd_i at [b][t][f]
// (f padded to FP, zero tail).
__global__ __launch_bounds__(256) void stft_kernel(
    const float* __restrict__ wave, const float* __restrict__ window,
    float* __restrict__ PL, float* __restrict__ PR,
    float* __restrict__ CR, float* __restrict__ CI)
{
  __shared__ float b0r[NFFT], b0i[NFFT], b1r[NFFT], b1i[NFFT];
  __shared__ float twr[NFFT / 2], twi[NFFT / 2];

  const int tid = threadIdx.x;
  const int bt  = blockIdx.x;
  const int b   = bt / TFRAMES;
  const int t   = bt - b * TFRAMES;

  for (int j = tid; j < NFFT / 2; j += 256) {
    float ang = -6.283185307179586f * (float)j / (float)NFFT;
    float sv, cv;
    sincosf(ang, &sv, &cv);
    twr[j] = cv; twi[j] = sv;
  }

  const float* wL = wave + ((size_t)b * 2 + 0) * NSAMP;
  const float* wR = wave + ((size_t)b * 2 + 1) * NSAMP;
  for (int j = tid; j < NFFT; j += 256) {
    int s0 = t * HOP - (NFFT / 2) + j;
    float wv = window[j];
    float vr = 0.0f, vi = 0.0f;
    if (s0 >= 0 && s0 < NSAMP) { vr = wL[s0] * wv; vi = wR[s0] * wv; }
    b0r[j] = vr; b0i[j] = vi;
  }
  __syncthreads();  // covers twiddles + frame

  float *sr = b0r, *si = b0i, *dr = b1r, *di = b1i;
  int s = 1;
  for (int stage = 0; stage < 11; ++stage) {
    #pragma unroll 4
    for (int i = tid; i < NFFT / 2; i += 256) {
      int ps = i & ~(s - 1);          // p*s  (twiddle index)
      int q  = i & (s - 1);
      float wr = twr[ps], wi = twi[ps];
      float ar = sr[i],            ai = si[i];
      float br = sr[i + NFFT / 2], bi = si[i + NFFT / 2];
      int d0 = (ps << 1) + q;
      dr[d0]     = ar + br;
      di[d0]     = ai + bi;
      float xr = ar - br, xi = ai - bi;
      dr[d0 + s] = xr * wr - xi * wi;
      di[d0 + s] = xr * wi + xi * wr;
    }
    __syncthreads();
    float* tp = sr; sr = dr; dr = tp;
    tp = si; si = di; di = tp;
    s <<= 1;
  }

  // result (natural order) in sr/si. Hermitian split:
  //   XL[k] = (Z[k] + conj(Z[N-k]))/2, XR[k] = -i(Z[k] - conj(Z[N-k]))/2
  size_t base = ((size_t)b * TFRAMES + t) * FP;
  for (int f = tid; f < FP; f += 256) {
    float pl = 0.f, pr = 0.f, cr = 0.f, ci = 0.f;
    if (f < NF) {
      int fc = (NFFT - f) & (NFFT - 1);
      float ar = sr[f],  ai = si[f];
      float br = sr[fc], bi = si[fc];
      float lr = 0.5f * (ar + br), li = 0.5f * (ai - bi);
      float rr = 0.5f * (ai + bi), ri = 0.5f * (br - ar);
      pl = lr * lr + li * li;
      pr = rr * rr + ri * ri;
      cr = lr * rr + li * ri;   // Re(XL * conj(XR))
      ci = li * rr - lr * ri;   // Im(XL * conj(XR))
    }
    PL[base + f] = pl; PR[base + f] = pr;
    CR[base + f] = cr; CI[base + f] = ci;
  }
}

// ---------------------------------------------------------------- direction GEMM
// corr_un = Wr*csd_r - Wi*csd_i ; n1 = hr*powL ; n2 = hl*powR ; fused epilogue:
// corr = corr_un / sqrt(n1*n2 + 1e-8), scatter-add into hrtf[b][az[d]][t].
__global__ __launch_bounds__(256) void dir_gemm(
    const float* __restrict__ Wr, const float* __restrict__ Wi,
    const float* __restrict__ Hr, const float* __restrict__ Hl,
    const float* __restrict__ PL, const float* __restrict__ PR,
    const float* __restrict__ CR, const float* __restrict__ CI,
    const int* __restrict__ az, float* __restrict__ hrtf)
{
  __shared__ float As[4][BK][LDT];
  __shared__ float Bs[4][BK][LDT];
  const int b  = blockIdx.z;
  const int d0 = blockIdx.y * 64;
  const int t0 = blockIdx.x * 64;
  const int tid = threadIdx.x;
  const int tx = tid & 15, ty = tid >> 4;

  float accC[4][4] = {}, acc1[4][4] = {}, acc2[4][4] = {};

  const int lr = tid >> 2;
  const int lk = (tid & 3) << 2;
  const float* Ap[4] = {Wr, Wi, Hr, Hl};
  const float* Bp[4] = {CR, CI, PL, PR};
  const size_t aoff = (size_t)(d0 + lr) * FP + lk;
  const size_t boff = ((size_t)b * TFRAMES + (t0 + lr)) * FP + lk;

  for (int k0 = 0; k0 < FP; k0 += BK) {
    #pragma unroll
    for (int m = 0; m < 4; ++m) {
      float4 a = *(const float4*)(Ap[m] + aoff + k0);
      As[m][lk + 0][lr] = a.x; As[m][lk + 1][lr] = a.y;
      As[m][lk + 2][lr] = a.z; As[m][lk + 3][lr] = a.w;
      float4 v = *(const float4*)(Bp[m] + boff + k0);
      Bs[m][lk + 0][lr] = v.x; Bs[m][lk + 1][lr] = v.y;
      Bs[m][lk + 2][lr] = v.z; Bs[m][lk + 3][lr] = v.w;
    }
    __syncthreads();
    #pragma unroll
    for (int kk = 0; kk < BK; ++kk) {
      float4 ar4 = *(const float4*)&As[0][kk][ty << 2];
      float4 ai4 = *(const float4*)&As[1][kk][ty << 2];
      float4 h14 = *(const float4*)&As[2][kk][ty << 2];
      float4 h24 = *(const float4*)&As[3][kk][ty << 2];
      float4 cr4 = *(const float4*)&Bs[0][kk][tx << 2];
      float4 ci4 = *(const float4*)&Bs[1][kk][tx << 2];
      float4 pl4 = *(const float4*)&Bs[2][kk][tx << 2];
      float4 pr4 = *(const float4*)&Bs[3][kk][tx << 2];
      const float* ar = (const float*)&ar4;  const float* ai = (const float*)&ai4;
      const float* h1 = (const float*)&h14;  const float* h2 = (const float*)&h24;
      const float* cr = (const float*)&cr4;  const float* ci = (const float*)&ci4;
      const float* pl = (const float*)&pl4;  const float* pr = (const float*)&pr4;
      #pragma unroll
      for (int i = 0; i < 4; ++i) {
        #pragma unroll
        for (int j = 0; j < 4; ++j) {
          accC[i][j] = fmaf(ar[i], cr[j], accC[i][j]);
          accC[i][j] = fmaf(-ai[i], ci[j], accC[i][j]);
          acc1[i][j] = fmaf(h1[i], pl[j], acc1[i][j]);
          acc2[i][j] = fmaf(h2[i], pr[j], acc2[i][j]);
        }
      }
    }
    __syncthreads();
  }

  int azv[4];
  #pragma unroll
  for (int i = 0; i < 4; ++i) azv[i] = az[d0 + (ty << 2) + i];
  #pragma unroll
  for (int i = 0; i < 4; ++i) {
    #pragma unroll
    for (int j = 0; j < 4; ++j) {
      int tcol = t0 + (tx << 2) + j;
      if (tcol < TFRAMES) {
        float cval = accC[i][j] / sqrtf(acc1[i][j] * acc2[i][j] + 1e-8f);
        unsafeAtomicAdd(hrtf + ((size_t)b * NMELS + azv[i]) * TFRAMES + tcol, cval);
      }
    }
  }
}

// ---------------------------------------------------------------- mel GEMM + ch0..ch4
__global__ __launch_bounds__(256) void mel_gemm(
    const float* __restrict__ MF,
    const float* __restrict__ PL, const float* __restrict__ PR,
    const float* __restrict__ CR, const float* __restrict__ CI,
    float* __restrict__ out)
{
  __shared__ float As[BK][LDT];
  __shared__ float Bs[4][BK][LDT];
  const int b  = blockIdx.y;
  const int t0 = blockIdx.x * 64;
  const int tid = threadIdx.x;
  const int tx = tid & 15, ty = tid >> 4;

  float aL[4][4] = {}, aR[4][4] = {}, aC[4][4] = {}, aI[4][4] = {};

  const int lr = tid >> 2;
  const int lk = (tid & 3) << 2;
  const float* Bp[4] = {PL, PR, CR, CI};
  const size_t boff = ((size_t)b * TFRAMES + (t0 + lr)) * FP + lk;

  for (int k0 = 0; k0 < FP; k0 += BK) {
    {
      float4 a = *(const float4*)(MF + (size_t)lr * FP + lk + k0);
      As[lk + 0][lr] = a.x; As[lk + 1][lr] = a.y;
      As[lk + 2][lr] = a.z; As[lk + 3][lr] = a.w;
    }
    #pragma unroll
    for (int m = 0; m < 4; ++m) {
      float4 v = *(const float4*)(Bp[m] + boff + k0);
      Bs[m][lk + 0][lr] = v.x; Bs[m][lk + 1][lr] = v.y;
      Bs[m][lk + 2][lr] = v.z; Bs[m][lk + 3][lr] = v.w;
    }
    __syncthreads();
    #pragma unroll
    for (int kk = 0; kk < BK; ++kk) {
      float4 mf4 = *(const float4*)&As[kk][ty << 2];
      float4 pl4 = *(const float4*)&Bs[0][kk][tx << 2];
      float4 pr4 = *(const float4*)&Bs[1][kk][tx << 2];
      float4 cr4 = *(const float4*)&Bs[2][kk][tx << 2];
      float4 ci4 = *(const float4*)&Bs[3][kk][tx << 2];
      const float* mf = (const float*)&mf4;
      const float* pl = (const float*)&pl4;  const float* pr = (const float*)&pr4;
      const float* cr = (const float*)&cr4;  const float* ci = (const float*)&ci4;
      #pragma unroll
      for (int i = 0; i < 4; ++i) {
        #pragma unroll
        for (int j = 0; j < 4; ++j) {
          aL[i][j] = fmaf(mf[i], pl[j], aL[i][j]);
          aR[i][j] = fmaf(mf[i], pr[j], aR[i][j]);
          aC[i][j] = fmaf(mf[i], cr[j], aC[i][j]);
          aI[i][j] = fmaf(mf[i], ci[j], aI[i][j]);
        }
      }
    }
    __syncthreads();
  }

  #pragma unroll
  for (int i = 0; i < 4; ++i) {
    int m = (ty << 2) + i;
    #pragma unroll
    for (int j = 0; j < 4; ++j) {
      int t = t0 + (tx << 2) + j;
      if (t < TFRAMES) {
        float mlv = aL[i][j], mrv = aR[i][j], crv = aC[i][j], civ = aI[i][j];
        float ch0 = 10.0f * log10f(mlv + 1e-8f);
        float ch1 = 10.0f * log10f(mrv + 1e-8f);
        float ch2 = 10.0f * log10f(mlv / (mrv + 1e-8f) + 1e-8f);
        float nrm = sqrtf(crv * crv + civ * civ + 1e-8f);
        float ch3 = civ / nrm;
        float ch4 = crv / nrm;
        size_t bb = (size_t)b * 6 * NMELS;
        out[((bb + 0 * NMELS + m)) * TFRAMES + t] = ch0;
        out[((bb + 1 * NMELS + m)) * TFRAMES + t] = ch1;
        out[((bb + 2 * NMELS + m)) * TFRAMES + t] = ch2;
        out[((bb + 3 * NMELS + m)) * TFRAMES + t] = ch3;
        out[((bb + 4 * NMELS + m)) * TFRAMES + t] = ch4;
      }
    }
  }
}

// ---------------------------------------------------------------- ch5 finalize
__global__ __launch_bounds__(256) void finalize_k(
    const float* __restrict__ hrtf, const int* __restrict__ az,
    float* __restrict__ out)
{
  __shared__ int red[256];
  const int m = blockIdx.x, b = blockIdx.y, tid = threadIdx.x;
  int c = 0;
  for (int j = tid; j < NDIR; j += 256) c += (az[j] == m) ? 1 : 0;
  red[tid] = c;
  __syncthreads();
  for (int st = 128; st > 0; st >>= 1) {
    if (tid < st) red[tid] += red[tid + st];
    __syncthreads();
  }
  float inv = 1.0f / ((float)red[0] + 1e-8f);
  const float* src = hrtf + ((size_t)b * NMELS + m) * TFRAMES;
  float* dst = out + (((size_t)b * 6 + 5) * NMELS + m) * TFRAMES;
  for (int t = tid; t < TFRAMES; t += 256) dst[t] = src[t] * inv;
}

// ---------------------------------------------------------------- launch
extern "C" void kernel_launch(void* const* d_in, const int* in_sizes, int n_in,
                              void* d_out, int out_size, void* d_ws, size_t ws_size,
                              hipStream_t stream) {
  const float* wave   = (const float*)d_in[0];
  const float* W_real = (const float*)d_in[1];
  const float* W_imag = (const float*)d_in[2];
  const float* Nhr    = (const float*)d_in[3];
  const float* Nhl    = (const float*)d_in[4];
  const int*   az     = (const int*)  d_in[5];
  const float* window = (const float*)d_in[6];
  const float* mel_fb = (const float*)d_in[7];
  float* out = (float*)d_out;

  float* ws  = (float*)d_ws;
  float* PL  = ws;
  float* PR  = PL + SZF;
  float* CR  = PR + SZF;
  float* CI  = CR + SZF;
  float* Wrp = CI + SZF;
  float* Wip = Wrp + SZW;
  float* Hrp = Wip + SZW;
  float* Hlp = Hrp + SZW;
  float* MFp = Hlp + SZW;
  float* hrtf = MFp + (size_t)NMELS * FP;

  hipMemsetAsync(hrtf, 0, sizeof(float) * BATCH * NMELS * TFRAMES, stream);

  int padBlocks = (NDIR * FP + 255) / 256;
  pad_copy_k<<<padBlocks, 256, 0, stream>>>(W_real, Wrp, NDIR);
  pad_copy_k<<<padBlocks, 256, 0, stream>>>(W_imag, Wip, NDIR);
  pad_copy_k<<<padBlocks, 256, 0, stream>>>(Nhr,    Hrp, NDIR);
  pad_copy_k<<<padBlocks, 256, 0, stream>>>(Nhl,    Hlp, NDIR);
  pad_copy_k<<<(NMELS * FP + 255) / 256, 256, 0, stream>>>(mel_fb, MFp, NMELS);

  stft_kernel<<<BATCH * TFRAMES, 256, 0, stream>>>(wave, window, PL, PR, CR, CI);

  dir_gemm<<<dim3(16, 36, BATCH), 256, 0, stream>>>(Wrp, Wip, Hrp, Hlp,
                                                    PL, PR, CR, CI, az, hrtf);

  mel_gemm<<<dim3(16, BATCH), 256, 0, stream>>>(MFp, PL, PR, CR, CI, out);

  finalize_k<<<dim3(NMELS, BATCH), 256, 0, stream>>>(hrtf, az, out);
}

// Round 4
// 908.089 us; speedup vs baseline: 3.0828x; 3.0828x over previous
//
#include <hip/hip_runtime.h>
#include <math.h>

#define NFFT    2048
#define HOP     960
#define NMELS   64
#define NDIR    2304
#define BATCH   8
#define NSAMP   960000
#define NF      1025
#define TFRAMES 1001
#define TP      1024      // padded t per batch (B-tile rows)
#define SEG     1056      // padded K segment (1025 -> 1056, mult of 32)
#define K2      2112      // concat CR||CI
#define BKM     16        // mel gemm K-step
#define LDT     68

typedef unsigned short ushort_t;
typedef __attribute__((ext_vector_type(8))) short bf16x8;
typedef __attribute__((ext_vector_type(4))) float f32x4;

// fp32 -> bf16 RNE
__device__ __forceinline__ ushort_t f2b(float x) {
  unsigned u = __float_as_uint(x);
  return (ushort_t)((u + 0x7FFFu + ((u >> 16) & 1u)) >> 16);
}
__device__ __forceinline__ float b2f(unsigned h) {
  return __uint_as_float(h << 16);
}

// ws element counts (floats first, then ushorts)
#define N_CORR ((size_t)BATCH * NDIR * TP)            // f32
#define N_HRTF ((size_t)BATCH * NMELS * TFRAMES)      // f32
#define N_MF   ((size_t)NMELS * SEG)                  // f32
#define N_FC   ((size_t)BATCH * TP * K2)              // ushorts
#define N_P    ((size_t)BATCH * TP * SEG)
#define N_AC   ((size_t)NDIR * K2)
#define N_AH   ((size_t)NDIR * SEG)

// ---------------------------------------------------------------- prep: split/pad A-side + mel_fb
__global__ __launch_bounds__(256) void prep_k(
    const float* __restrict__ Wr, const float* __restrict__ Wi,
    const float* __restrict__ Hr, const float* __restrict__ Hl,
    const float* __restrict__ mfb,
    ushort_t* __restrict__ ACh, ushort_t* __restrict__ ACl,
    ushort_t* __restrict__ AHrh, ushort_t* __restrict__ AHrl,
    ushort_t* __restrict__ AHlh, ushort_t* __restrict__ AHll,
    float* __restrict__ MFp)
{
  const size_t n1 = (size_t)NDIR * K2, n2 = (size_t)NDIR * SEG;
  const size_t tot = n1 + 2 * n2 + (size_t)NMELS * SEG;
  for (size_t idx = blockIdx.x * 256 + threadIdx.x; idx < tot; idx += (size_t)gridDim.x * 256) {
    if (idx < n1) {                       // AC = [Wr | -Wi], K2
      int d = idx / K2, k2 = idx - (size_t)d * K2;
      float w;
      if (k2 < SEG) w = (k2 < NF) ? Wr[(size_t)d * NF + k2] : 0.0f;
      else { int kk = k2 - SEG; w = (kk < NF) ? -Wi[(size_t)d * NF + kk] : 0.0f; }
      ushort_t h = f2b(w);
      ACh[idx] = h; ACl[idx] = f2b(w - b2f(h));
    } else if (idx < n1 + n2) {           // Hr (pairs with powL)
      size_t i = idx - n1; int d = i / SEG, k = i - (size_t)d * SEG;
      float w = (k < NF) ? Hr[(size_t)d * NF + k] : 0.0f;
      ushort_t h = f2b(w);
      AHrh[i] = h; AHrl[i] = f2b(w - b2f(h));
    } else if (idx < n1 + 2 * n2) {       // Hl (pairs with powR)
      size_t i = idx - n1 - n2; int d = i / SEG, k = i - (size_t)d * SEG;
      float w = (k < NF) ? Hl[(size_t)d * NF + k] : 0.0f;
      ushort_t h = f2b(w);
      AHlh[i] = h; AHll[i] = f2b(w - b2f(h));
    } else {                              // mel_fb fp32 padded
      size_t i = idx - n1 - 2 * n2; int m = i / SEG, k = i - (size_t)m * SEG;
      MFp[i] = (k < NF) ? mfb[(size_t)m * NF + k] : 0.0f;
    }
  }
}

// ---------------------------------------------------------------- STFT + features (bf16 out)
// Two-for-one: z = xL + i*xR, one 2048-pt Stockham FFT, Hermitian split.
// PLh/PRh: bf16 hi only. CR/CI: hi (FCh) + lo (FCl) pairs for mel accuracy.
__global__ __launch_bounds__(256) void stft_kernel(
    const float* __restrict__ wave, const float* __restrict__ window,
    ushort_t* __restrict__ PLh, ushort_t* __restrict__ PRh,
    ushort_t* __restrict__ FCh, ushort_t* __restrict__ FCl)
{
  __shared__ float b0r[NFFT], b0i[NFFT], b1r[NFFT], b1i[NFFT];
  __shared__ float twr[NFFT / 2], twi[NFFT / 2];

  const int tid = threadIdx.x;
  const int bt  = blockIdx.x;
  const int b   = bt / TFRAMES;
  const int t   = bt - b * TFRAMES;

  for (int j = tid; j < NFFT / 2; j += 256) {
    float ang = -6.283185307179586f * (float)j / (float)NFFT;
    float sv, cv; sincosf(ang, &sv, &cv);
    twr[j] = cv; twi[j] = sv;
  }
  const float* wL = wave + ((size_t)b * 2 + 0) * NSAMP;
  const float* wR = wave + ((size_t)b * 2 + 1) * NSAMP;
  for (int j = tid; j < NFFT; j += 256) {
    int s0 = t * HOP - (NFFT / 2) + j;
    float wv = window[j];
    float vr = 0.0f, vi = 0.0f;
    if (s0 >= 0 && s0 < NSAMP) { vr = wL[s0] * wv; vi = wR[s0] * wv; }
    b0r[j] = vr; b0i[j] = vi;
  }
  __syncthreads();

  float *sr = b0r, *si = b0i, *dr = b1r, *di = b1i;
  int s = 1;
  for (int stage = 0; stage < 11; ++stage) {
    #pragma unroll 4
    for (int i = tid; i < NFFT / 2; i += 256) {
      int ps = i & ~(s - 1), q = i & (s - 1);
      float wr = twr[ps], wi = twi[ps];
      float ar = sr[i], ai = si[i];
      float br = sr[i + NFFT / 2], bi = si[i + NFFT / 2];
      int d0 = (ps << 1) + q;
      dr[d0] = ar + br; di[d0] = ai + bi;
      float xr = ar - br, xi = ai - bi;
      dr[d0 + s] = xr * wr - xi * wi;
      di[d0 + s] = xr * wi + xi * wr;
    }
    __syncthreads();
    float* tp = sr; sr = dr; dr = tp;
    tp = si; si = di; di = tp;
    s <<= 1;
  }

  const size_t rb = (size_t)b * TP + t;
  for (int f = tid; f < SEG; f += 256) {
    float pl = 0.f, pr = 0.f, cr = 0.f, ci = 0.f;
    if (f < NF) {
      int fc = (NFFT - f) & (NFFT - 1);
      float ar = sr[f], ai = si[f];
      float br = sr[fc], bi = si[fc];
      float lr = 0.5f * (ar + br), li = 0.5f * (ai - bi);
      float rr = 0.5f * (ai + bi), ri = 0.5f * (br - ar);
      pl = lr * lr + li * li;
      pr = rr * rr + ri * ri;
      cr = lr * rr + li * ri;
      ci = li * rr - lr * ri;
    }
    PLh[rb * SEG + f] = f2b(pl);
    PRh[rb * SEG + f] = f2b(pr);
    ushort_t crh = f2b(cr), cih = f2b(ci);
    FCh[rb * K2 + f]       = crh;
    FCh[rb * K2 + SEG + f] = cih;
    FCl[rb * K2 + f]       = f2b(cr - b2f(crh));
    FCl[rb * K2 + SEG + f] = f2b(ci - b2f(cih));
  }
}

// async global->LDS, 16B per lane, wave-uniform LDS base
#define GL16(gp, loff) \
  __builtin_amdgcn_global_load_lds((const __attribute__((address_space(1))) void*)(gp), \
      (__attribute__((address_space(3))) void*)(smem + (loff)), 16, 0, 0)

// ---------------------------------------------------------------- C-GEMM: corr_un = [Wr|-Wi] . [CR;CI]
// 128x128 tile, BK=32, 4 waves of 64x64, 16x16x32 bf16 MFMA, A hi/lo x B hi (2 passes).
__global__ __launch_bounds__(256, 2) void gemm_c(
    const ushort_t* __restrict__ Ah, const ushort_t* __restrict__ Al,
    const ushort_t* __restrict__ Bh, float* __restrict__ Cout)
{
  __shared__ __align__(16) char smem[24576];  // Ah 0 | Al 8K | Bh 16K
  const int tid = threadIdx.x;
  const int wave = tid >> 6, lane = tid & 63;
  const int b  = blockIdx.z;
  const int d0 = blockIdx.y * 128;
  const int t0 = blockIdx.x * 128;
  const int wr = wave >> 1, wc = wave & 1;

  const int srow = lane >> 2;
  const int skb  = (lane & 3) * 8;
  const int c0 = wave, c1 = wave + 4;
  const size_t ar0 = (size_t)(d0 + c0 * 16 + srow) * K2 + skb;
  const size_t ar1 = (size_t)(d0 + c1 * 16 + srow) * K2 + skb;
  const size_t br0 = ((size_t)b * TP + t0 + c0 * 16 + srow) * K2 + skb;
  const size_t br1 = ((size_t)b * TP + t0 + c1 * 16 + srow) * K2 + skb;

  f32x4 acc[4][4];
  #pragma unroll
  for (int i = 0; i < 4; ++i)
    #pragma unroll
    for (int j = 0; j < 4; ++j) acc[i][j] = (f32x4){0.f, 0.f, 0.f, 0.f};

  const int frow = (lane & 15) * 64;   // LDS row byte offset
  const int fk   = (lane >> 4) * 16;   // LDS k-chunk byte offset

  for (int k0 = 0; k0 < K2; k0 += 32) {
    GL16(Ah + ar0 + k0, 0     + c0 * 1024);
    GL16(Ah + ar1 + k0, 0     + c1 * 1024);
    GL16(Al + ar0 + k0, 8192  + c0 * 1024);
    GL16(Al + ar1 + k0, 8192  + c1 * 1024);
    GL16(Bh + br0 + k0, 16384 + c0 * 1024);
    GL16(Bh + br1 + k0, 16384 + c1 * 1024);
    __syncthreads();
    bf16x8 ah[4], al[4], bh[4];
    #pragma unroll
    for (int f = 0; f < 4; ++f) {
      ah[f] = *(const bf16x8*)(smem +         wr * 4096 + f * 1024 + frow + fk);
      al[f] = *(const bf16x8*)(smem + 8192  + wr * 4096 + f * 1024 + frow + fk);
      bh[f] = *(const bf16x8*)(smem + 16384 + wc * 4096 + f * 1024 + frow + fk);
    }
    #pragma unroll
    for (int i = 0; i < 4; ++i)
      #pragma unroll
      for (int j = 0; j < 4; ++j) {
        acc[i][j] = __builtin_amdgcn_mfma_f32_16x16x32_bf16(ah[i], bh[j], acc[i][j], 0, 0, 0);
        acc[i][j] = __builtin_amdgcn_mfma_f32_16x16x32_bf16(al[i], bh[j], acc[i][j], 0, 0, 0);
      }
    __syncthreads();
  }

  const int orow = (lane >> 4) * 4, ocol = lane & 15;
  #pragma unroll
  for (int i = 0; i < 4; ++i) {
    int d = d0 + wr * 64 + i * 16 + orow;
    #pragma unroll
    for (int j = 0; j < 4; ++j) {
      int t = t0 + wc * 64 + j * 16 + ocol;
      float* p = Cout + ((size_t)b * NDIR + d) * TP + t;
      #pragma unroll
      for (int r = 0; r < 4; ++r) p[(size_t)r * TP] = acc[i][j][r];
    }
  }
}

// ---------------------------------------------------------------- n1/n2 GEMM + fused epilogue
// n1 = Hr.PL, n2 = Hl.PR; corr = corr_un / sqrt(n1*n2+1e-8); atomic scatter by az.
__global__ __launch_bounds__(256, 2) void gemm_n12(
    const ushort_t* __restrict__ A1h, const ushort_t* __restrict__ A1l,
    const ushort_t* __restrict__ A2h, const ushort_t* __restrict__ A2l,
    const ushort_t* __restrict__ B1,  const ushort_t* __restrict__ B2,
    const float* __restrict__ corr_un, const int* __restrict__ az,
    float* __restrict__ hrtf)
{
  __shared__ __align__(16) char smem[49152]; // A1h|A1l|A2h|A2l|B1|B2 (8K each)
  const int tid = threadIdx.x;
  const int wave = tid >> 6, lane = tid & 63;
  const int b  = blockIdx.z;
  const int d0 = blockIdx.y * 128;
  const int t0 = blockIdx.x * 128;
  const int wr = wave >> 1, wc = wave & 1;

  const int srow = lane >> 2;
  const int skb  = (lane & 3) * 8;
  const int c0 = wave, c1 = wave + 4;
  const size_t ar0 = (size_t)(d0 + c0 * 16 + srow) * SEG + skb;
  const size_t ar1 = (size_t)(d0 + c1 * 16 + srow) * SEG + skb;
  const size_t br0 = ((size_t)b * TP + t0 + c0 * 16 + srow) * SEG + skb;
  const size_t br1 = ((size_t)b * TP + t0 + c1 * 16 + srow) * SEG + skb;

  f32x4 acc1[4][4], acc2[4][4];
  #pragma unroll
  for (int i = 0; i < 4; ++i)
    #pragma unroll
    for (int j = 0; j < 4; ++j) {
      acc1[i][j] = (f32x4){0.f, 0.f, 0.f, 0.f};
      acc2[i][j] = (f32x4){0.f, 0.f, 0.f, 0.f};
    }

  const int frow = (lane & 15) * 64;
  const int fk   = (lane >> 4) * 16;

  for (int k0 = 0; k0 < SEG; k0 += 32) {
    GL16(A1h + ar0 + k0, 0     + c0 * 1024);
    GL16(A1h + ar1 + k0, 0     + c1 * 1024);
    GL16(A1l + ar0 + k0, 8192  + c0 * 1024);
    GL16(A1l + ar1 + k0, 8192  + c1 * 1024);
    GL16(A2h + ar0 + k0, 16384 + c0 * 1024);
    GL16(A2h + ar1 + k0, 16384 + c1 * 1024);
    GL16(A2l + ar0 + k0, 24576 + c0 * 1024);
    GL16(A2l + ar1 + k0, 24576 + c1 * 1024);
    GL16(B1  + br0 + k0, 32768 + c0 * 1024);
    GL16(B1  + br1 + k0, 32768 + c1 * 1024);
    GL16(B2  + br0 + k0, 40960 + c0 * 1024);
    GL16(B2  + br1 + k0, 40960 + c1 * 1024);
    __syncthreads();
    bf16x8 b1f[4], b2f_[4];
    #pragma unroll
    for (int f = 0; f < 4; ++f) {
      b1f[f]  = *(const bf16x8*)(smem + 32768 + wc * 4096 + f * 1024 + frow + fk);
      b2f_[f] = *(const bf16x8*)(smem + 40960 + wc * 4096 + f * 1024 + frow + fk);
    }
    #pragma unroll
    for (int i = 0; i < 4; ++i) {
      bf16x8 a1h = *(const bf16x8*)(smem +         wr * 4096 + i * 1024 + frow + fk);
      bf16x8 a1l = *(const bf16x8*)(smem + 8192  + wr * 4096 + i * 1024 + frow + fk);
      bf16x8 a2h = *(const bf16x8*)(smem + 16384 + wr * 4096 + i * 1024 + frow + fk);
      bf16x8 a2l = *(const bf16x8*)(smem + 24576 + wr * 4096 + i * 1024 + frow + fk);
      #pragma unroll
      for (int j = 0; j < 4; ++j) {
        acc1[i][j] = __builtin_amdgcn_mfma_f32_16x16x32_bf16(a1h, b1f[j],  acc1[i][j], 0, 0, 0);
        acc1[i][j] = __builtin_amdgcn_mfma_f32_16x16x32_bf16(a1l, b1f[j],  acc1[i][j], 0, 0, 0);
        acc2[i][j] = __builtin_amdgcn_mfma_f32_16x16x32_bf16(a2h, b2f_[j], acc2[i][j], 0, 0, 0);
        acc2[i][j] = __builtin_amdgcn_mfma_f32_16x16x32_bf16(a2l, b2f_[j], acc2[i][j], 0, 0, 0);
      }
    }
    __syncthreads();
  }

  const int orow = (lane >> 4) * 4, ocol = lane & 15;
  #pragma unroll
  for (int i = 0; i < 4; ++i) {
    int dbase = d0 + wr * 64 + i * 16 + orow;
    #pragma unroll
    for (int j = 0; j < 4; ++j) {
      int t = t0 + wc * 64 + j * 16 + ocol;
      if (t < TFRAMES) {
        #pragma unroll
        for (int r = 0; r < 4; ++r) {
          int d = dbase + r;
          float n1 = acc1[i][j][r], n2 = acc2[i][j][r];
          float cu = corr_un[((size_t)b * NDIR + d) * TP + t];
          float cval = cu / sqrtf(n1 * n2 + 1e-8f);
          unsafeAtomicAdd(hrtf + ((size_t)b * NMELS + az[d]) * TFRAMES + t, cval);
        }
      }
    }
  }
}

// ---------------------------------------------------------------- mel GEMM + ch0..ch4 (fp32 acc)
// PL/PR: bf16 hi (positive sums, 0.2% rel ok). CR/CI: hi+lo reconstruct (~fp32).
__global__ __launch_bounds__(256) void mel_gemm(
    const float* __restrict__ MF,
    const ushort_t* __restrict__ PLh, const ushort_t* __restrict__ PRh,
    const ushort_t* __restrict__ FCh, const ushort_t* __restrict__ FCl,
    float* __restrict__ out)
{
  __shared__ float As[BKM][LDT];
  __shared__ float Bs[4][BKM][LDT];
  const int b  = blockIdx.y;
  const int t0 = blockIdx.x * 64;
  const int tid = threadIdx.x;
  const int tx = tid & 15, ty = tid >> 4;
  const int lr = tid >> 2, lk = (tid & 3) * 4;

  float aL[4][4] = {}, aR[4][4] = {}, aC[4][4] = {}, aI[4][4] = {};

  const size_t rb = (size_t)b * TP + t0 + lr;
  const ushort_t* Bp[4] = {PLh, PRh, FCh, FCh + SEG};
  const ushort_t* Bl[4] = {PLh, PRh, FCl, FCl + SEG};   // [0],[1] unused
  const size_t   Bst[4] = {SEG, SEG, K2, K2};

  for (int k0 = 0; k0 < SEG; k0 += BKM) {
    {
      float4 a = *(const float4*)(MF + (size_t)lr * SEG + k0 + lk);
      As[lk + 0][lr] = a.x; As[lk + 1][lr] = a.y;
      As[lk + 2][lr] = a.z; As[lk + 3][lr] = a.w;
    }
    #pragma unroll
    for (int m = 0; m < 4; ++m) {
      uint2 v = *(const uint2*)(Bp[m] + rb * Bst[m] + k0 + lk);
      float f0 = b2f(v.x & 0xffffu), f1 = b2f(v.x >> 16);
      float f2 = b2f(v.y & 0xffffu), f3 = b2f(v.y >> 16);
      if (m >= 2) {
        uint2 w = *(const uint2*)(Bl[m] + rb * Bst[m] + k0 + lk);
        f0 += b2f(w.x & 0xffffu); f1 += b2f(w.x >> 16);
        f2 += b2f(w.y & 0xffffu); f3 += b2f(w.y >> 16);
      }
      Bs[m][lk + 0][lr] = f0; Bs[m][lk + 1][lr] = f1;
      Bs[m][lk + 2][lr] = f2; Bs[m][lk + 3][lr] = f3;
    }
    __syncthreads();
    #pragma unroll
    for (int kk = 0; kk < BKM; ++kk) {
      float4 mf4 = *(const float4*)&As[kk][ty << 2];
      float4 pl4 = *(const float4*)&Bs[0][kk][tx << 2];
      float4 pr4 = *(const float4*)&Bs[1][kk][tx << 2];
      float4 cr4 = *(const float4*)&Bs[2][kk][tx << 2];
      float4 ci4 = *(const float4*)&Bs[3][kk][tx << 2];
      const float* mf = (const float*)&mf4;
      const float* pl = (const float*)&pl4; const float* pr = (const float*)&pr4;
      const float* cr = (const float*)&cr4; const float* ci = (const float*)&ci4;
      #pragma unroll
      for (int i = 0; i < 4; ++i)
        #pragma unroll
        for (int j = 0; j < 4; ++j) {
          aL[i][j] = fmaf(mf[i], pl[j], aL[i][j]);
          aR[i][j] = fmaf(mf[i], pr[j], aR[i][j]);
          aC[i][j] = fmaf(mf[i], cr[j], aC[i][j]);
          aI[i][j] = fmaf(mf[i], ci[j], aI[i][j]);
        }
    }
    __syncthreads();
  }

  #pragma unroll
  for (int i = 0; i < 4; ++i) {
    int m = (ty << 2) + i;
    #pragma unroll
    for (int j = 0; j < 4; ++j) {
      int t = t0 + (tx << 2) + j;
      if (t < TFRAMES) {
        float mlv = aL[i][j], mrv = aR[i][j], crv = aC[i][j], civ = aI[i][j];
        float ch0 = 10.0f * log10f(mlv + 1e-8f);
        float ch1 = 10.0f * log10f(mrv + 1e-8f);
        float ch2 = 10.0f * log10f(mlv / (mrv + 1e-8f) + 1e-8f);
        float nrm = sqrtf(crv * crv + civ * civ + 1e-8f);
        float ch3 = civ / nrm;
        float ch4 = crv / nrm;
        size_t bb = (size_t)b * 6 * NMELS;
        out[(bb + 0 * NMELS + m) * TFRAMES + t] = ch0;
        out[(bb + 1 * NMELS + m) * TFRAMES + t] = ch1;
        out[(bb + 2 * NMELS + m) * TFRAMES + t] = ch2;
        out[(bb + 3 * NMELS + m) * TFRAMES + t] = ch3;
        out[(bb + 4 * NMELS + m) * TFRAMES + t] = ch4;
      }
    }
  }
}

// ---------------------------------------------------------------- ch5 finalize
__global__ __launch_bounds__(256) void finalize_k(
    const float* __restrict__ hrtf, const int* __restrict__ az,
    float* __restrict__ out)
{
  __shared__ int red[256];
  const int m = blockIdx.x, b = blockIdx.y, tid = threadIdx.x;
  int c = 0;
  for (int j = tid; j < NDIR; j += 256) c += (az[j] == m) ? 1 : 0;
  red[tid] = c;
  __syncthreads();
  for (int st = 128; st > 0; st >>= 1) {
    if (tid < st) red[tid] += red[tid + st];
    __syncthreads();
  }
  float inv = 1.0f / ((float)red[0] + 1e-8f);
  const float* src = hrtf + ((size_t)b * NMELS + m) * TFRAMES;
  float* dst = out + (((size_t)b * 6 + 5) * NMELS + m) * TFRAMES;
  for (int t = tid; t < TFRAMES; t += 256) dst[t] = src[t] * inv;
}

// ---------------------------------------------------------------- launch
extern "C" void kernel_launch(void* const* d_in, const int* in_sizes, int n_in,
                              void* d_out, int out_size, void* d_ws, size_t ws_size,
                              hipStream_t stream) {
  const float* wave   = (const float*)d_in[0];
  const float* W_real = (const float*)d_in[1];
  const float* W_imag = (const float*)d_in[2];
  const float* Nhr    = (const float*)d_in[3];
  const float* Nhl    = (const float*)d_in[4];
  const int*   az     = (const int*)  d_in[5];
  const float* window = (const float*)d_in[6];
  const float* mel_fb = (const float*)d_in[7];
  float* out = (float*)d_out;

  // layout: [corr_un f32][hrtf f32][MFp f32][bf16 arrays...]  (~210 MiB total)
  float* fw = (float*)d_ws;
  float* corr_un = fw;
  float* hrtf    = corr_un + N_CORR;
  float* MFp     = hrtf + N_HRTF;
  ushort_t* ub   = (ushort_t*)(MFp + N_MF);
  ushort_t* FCh  = ub;
  ushort_t* FCl  = FCh + N_FC;
  ushort_t* PLh  = FCl + N_FC;
  ushort_t* PRh  = PLh + N_P;
  ushort_t* ACh  = PRh + N_P;
  ushort_t* ACl  = ACh + N_AC;
  ushort_t* AHrh = ACl + N_AC;
  ushort_t* AHrl = AHrh + N_AH;
  ushort_t* AHlh = AHrl + N_AH;
  ushort_t* AHll = AHlh + N_AH;

  hipMemsetAsync(hrtf, 0, sizeof(float) * N_HRTF, stream);

  prep_k<<<2048, 256, 0, stream>>>(W_real, W_imag, Nhr, Nhl, mel_fb,
                                   ACh, ACl, AHrh, AHrl, AHlh, AHll, MFp);

  stft_kernel<<<BATCH * TFRAMES, 256, 0, stream>>>(wave, window, PLh, PRh, FCh, FCl);

  gemm_c<<<dim3(8, 18, BATCH), 256, 0, stream>>>(ACh, ACl, FCh, corr_un);

  gemm_n12<<<dim3(8, 18, BATCH), 256, 0, stream>>>(AHrh, AHrl, AHlh, AHll,
                                                   PLh, PRh, corr_un, az, hrtf);

  mel_gemm<<<dim3(16, BATCH), 256, 0, stream>>>(MFp, PLh, PRh, FCh, FCl, out);

  finalize_k<<<dim3(NMELS, BATCH), 256, 0, stream>>>(hrtf, az, out);
}

// Round 8
// 757.383 us; speedup vs baseline: 3.6962x; 1.1990x over previous
//
#include <hip/hip_runtime.h>
#include <math.h>

#define NFFT    2048
#define HOP     960
#define NMELS   64
#define NDIR    2304
#define BATCH   8
#define NSAMP   960000
#define NF      1025
#define TFRAMES 1001
#define TP      1024      // padded t per batch
#define SEG     1056      // padded K (1025 -> mult of 32)
#define K2      2112      // concat CR||CI
#define BKM     16
#define LDT     68
#define NWG     1152      // 18 d-tiles x 8 t-tiles x 8 batches

typedef unsigned short ushort_t;
typedef __attribute__((ext_vector_type(8))) short bf16x8;
typedef __attribute__((ext_vector_type(4))) float f32x4;

__device__ __forceinline__ ushort_t f2b(float x) {
  unsigned u = __float_as_uint(x);
  return (ushort_t)((u + 0x7FFFu + ((u >> 16) & 1u)) >> 16);
}
__device__ __forceinline__ float b2f(unsigned h) {
  return __uint_as_float(h << 16);
}

#define N_HRTF ((size_t)BATCH * NMELS * TFRAMES)      // f32
#define N_MF   ((size_t)NMELS * SEG)                  // f32
#define N_CORR ((size_t)BATCH * NDIR * TP)            // ushort (bf16)
#define N_FC   ((size_t)BATCH * TP * K2)              // ushort
#define N_P    ((size_t)BATCH * TP * SEG)             // ushort
#define N_AC   ((size_t)NDIR * K2)                    // ushort
#define N_AH   ((size_t)NDIR * SEG)                   // ushort

// ---------------------------------------------------------------- prep (bf16-hi A panels + mel fb)
__global__ __launch_bounds__(256) void prep_k(
    const float* __restrict__ Wr, const float* __restrict__ Wi,
    const float* __restrict__ Hr, const float* __restrict__ Hl,
    const float* __restrict__ mfb,
    ushort_t* __restrict__ ACh, ushort_t* __restrict__ AHrh,
    ushort_t* __restrict__ AHlh, float* __restrict__ MFp)
{
  const size_t n1 = (size_t)NDIR * K2, n2 = (size_t)NDIR * SEG;
  const size_t tot = n1 + 2 * n2 + (size_t)NMELS * SEG;
  for (size_t idx = blockIdx.x * 256 + threadIdx.x; idx < tot; idx += (size_t)gridDim.x * 256) {
    if (idx < n1) {                       // AC = [Wr | -Wi]
      int d = idx / K2, k2 = idx - (size_t)d * K2;
      float w;
      if (k2 < SEG) w = (k2 < NF) ? Wr[(size_t)d * NF + k2] : 0.0f;
      else { int kk = k2 - SEG; w = (kk < NF) ? -Wi[(size_t)d * NF + kk] : 0.0f; }
      ACh[idx] = f2b(w);
    } else if (idx < n1 + n2) {
      size_t i = idx - n1; int d = i / SEG, k = i - (size_t)d * SEG;
      AHrh[i] = f2b((k < NF) ? Hr[(size_t)d * NF + k] : 0.0f);
    } else if (idx < n1 + 2 * n2) {
      size_t i = idx - n1 - n2; int d = i / SEG, k = i - (size_t)d * SEG;
      AHlh[i] = f2b((k < NF) ? Hl[(size_t)d * NF + k] : 0.0f);
    } else {
      size_t i = idx - n1 - 2 * n2; int m = i / SEG, k = i - (size_t)m * SEG;
      MFp[i] = (k < NF) ? mfb[(size_t)m * NF + k] : 0.0f;
    }
  }
}

// ---------------------------------------------------------------- STFT + features
__global__ __launch_bounds__(256) void stft_kernel(
    const float* __restrict__ wave, const float* __restrict__ window,
    ushort_t* __restrict__ PLh, ushort_t* __restrict__ PRh,
    ushort_t* __restrict__ FCh, ushort_t* __restrict__ FCl)
{
  __shared__ float b0r[NFFT], b0i[NFFT], b1r[NFFT], b1i[NFFT];
  __shared__ float twr[NFFT / 2], twi[NFFT / 2];

  const int tid = threadIdx.x;
  const int bt  = blockIdx.x;
  const int b   = bt / TFRAMES;
  const int t   = bt - b * TFRAMES;

  for (int j = tid; j < NFFT / 2; j += 256) {
    float ang = -6.283185307179586f * (float)j / (float)NFFT;
    float sv, cv; sincosf(ang, &sv, &cv);
    twr[j] = cv; twi[j] = sv;
  }
  const float* wL = wave + ((size_t)b * 2 + 0) * NSAMP;
  const float* wR = wave + ((size_t)b * 2 + 1) * NSAMP;
  for (int j = tid; j < NFFT; j += 256) {
    int s0 = t * HOP - (NFFT / 2) + j;
    float wv = window[j];
    float vr = 0.0f, vi = 0.0f;
    if (s0 >= 0 && s0 < NSAMP) { vr = wL[s0] * wv; vi = wR[s0] * wv; }
    b0r[j] = vr; b0i[j] = vi;
  }
  __syncthreads();

  float *sr = b0r, *si = b0i, *dr = b1r, *di = b1i;
  int s = 1;
  for (int stage = 0; stage < 11; ++stage) {
    #pragma unroll 4
    for (int i = tid; i < NFFT / 2; i += 256) {
      int ps = i & ~(s - 1), q = i & (s - 1);
      float wr = twr[ps], wi = twi[ps];
      float ar = sr[i], ai = si[i];
      float br = sr[i + NFFT / 2], bi = si[i + NFFT / 2];
      int d0 = (ps << 1) + q;
      dr[d0] = ar + br; di[d0] = ai + bi;
      float xr = ar - br, xi = ai - bi;
      dr[d0 + s] = xr * wr - xi * wi;
      di[d0 + s] = xr * wi + xi * wr;
    }
    __syncthreads();
    float* tp = sr; sr = dr; dr = tp;
    tp = si; si = di; di = tp;
    s <<= 1;
  }

  const size_t rb = (size_t)b * TP + t;
  for (int f = tid; f < SEG; f += 256) {
    float pl = 0.f, pr = 0.f, cr = 0.f, ci = 0.f;
    if (f < NF) {
      int fc = (NFFT - f) & (NFFT - 1);
      float ar = sr[f], ai = si[f];
      float br = sr[fc], bi = si[fc];
      float lr = 0.5f * (ar + br), li = 0.5f * (ai - bi);
      float rr = 0.5f * (ai + bi), ri = 0.5f * (br - ar);
      pl = lr * lr + li * li;
      pr = rr * rr + ri * ri;
      cr = lr * rr + li * ri;
      ci = li * rr - lr * ri;
    }
    PLh[rb * SEG + f] = f2b(pl);
    PRh[rb * SEG + f] = f2b(pr);
    ushort_t crh = f2b(cr), cih = f2b(ci);
    FCh[rb * K2 + f]       = crh;
    FCh[rb * K2 + SEG + f] = cih;
    FCl[rb * K2 + f]       = f2b(cr - b2f(crh));
    FCl[rb * K2 + SEG + f] = f2b(ci - b2f(cih));
  }
}

#define GL16(gp, loff) \
  __builtin_amdgcn_global_load_lds((const __attribute__((address_space(1))) void*)(gp), \
      (__attribute__((address_space(3))) void*)(smem + (loff)), 16, 0, 0)

// XCD-aware bijective block swizzle (NWG % 8 == 0): consecutive logical ids
// (18 d-tiles sharing one B panel) stay on one XCD -> B panel L2-resident.
#define XCD_DECODE() \
  int logical = (blockIdx.x & 7) * (NWG / 8) + (blockIdx.x >> 3); \
  int dt = logical % 18; int rq = logical / 18;                   \
  int tt = rq & 7; int b = rq >> 3;                               \
  const int d0 = dt * 128; const int t0 = tt * 128;

// ---------------------------------------------------------------- corr_un GEMM (m97-clone)
// corr_un[b][d][t] (bf16) = [Wr|-Wi] . [CR;CI], K2=2112, A/B bf16-hi.
__global__ __launch_bounds__(256, 3) void gemm_c(
    const ushort_t* __restrict__ A, const ushort_t* __restrict__ B,
    ushort_t* __restrict__ Cout)
{
  __shared__ __align__(16) char smem[16384];  // A 8K | B 8K
  const int tid = threadIdx.x;
  const int wave = tid >> 6, lane = tid & 63;
  XCD_DECODE();
  const int wr = wave >> 1, wc = wave & 1;

  const int srow = lane >> 2, skb = (lane & 3) * 8;
  const int c0 = wave, c1 = wave + 4;
  const size_t ar0 = (size_t)(d0 + c0 * 16 + srow) * K2 + skb;
  const size_t ar1 = (size_t)(d0 + c1 * 16 + srow) * K2 + skb;
  const size_t br0 = ((size_t)b * TP + t0 + c0 * 16 + srow) * K2 + skb;
  const size_t br1 = ((size_t)b * TP + t0 + c1 * 16 + srow) * K2 + skb;

  f32x4 acc[4][4];
  #pragma unroll
  for (int i = 0; i < 4; ++i)
    #pragma unroll
    for (int j = 0; j < 4; ++j) acc[i][j] = (f32x4){0.f, 0.f, 0.f, 0.f};

  const int frow = (lane & 15) * 64, fk = (lane >> 4) * 16;

  for (int k0 = 0; k0 < K2; k0 += 32) {
    GL16(A + ar0 + k0, 0    + c0 * 1024);
    GL16(A + ar1 + k0, 0    + c1 * 1024);
    GL16(B + br0 + k0, 8192 + c0 * 1024);
    GL16(B + br1 + k0, 8192 + c1 * 1024);
    __syncthreads();
    bf16x8 af[4], bf[4];
    #pragma unroll
    for (int f = 0; f < 4; ++f) {
      af[f] = *(const bf16x8*)(smem +        wr * 4096 + f * 1024 + frow + fk);
      bf[f] = *(const bf16x8*)(smem + 8192 + wc * 4096 + f * 1024 + frow + fk);
    }
    #pragma unroll
    for (int i = 0; i < 4; ++i)
      #pragma unroll
      for (int j = 0; j < 4; ++j)
        acc[i][j] = __builtin_amdgcn_mfma_f32_16x16x32_bf16(af[i], bf[j], acc[i][j], 0, 0, 0);
    __syncthreads();
  }

  const int orow = (lane >> 4) * 4, ocol = lane & 15;
  #pragma unroll
  for (int i = 0; i < 4; ++i) {
    int d = d0 + wr * 64 + i * 16 + orow;
    #pragma unroll
    for (int j = 0; j < 4; ++j) {
      int t = t0 + wc * 64 + j * 16 + ocol;
      ushort_t* p = Cout + ((size_t)b * NDIR + d) * TP + t;
      #pragma unroll
      for (int r = 0; r < 4; ++r) p[(size_t)r * TP] = f2b(acc[i][j][r]);
    }
  }
}

// ---------------------------------------------------------------- n1 GEMM (m97-clone): n1 = Hr.PL -> bf16
__global__ __launch_bounds__(256, 3) void gemm_n1(
    const ushort_t* __restrict__ A, const ushort_t* __restrict__ B,
    ushort_t* __restrict__ N1)
{
  __shared__ __align__(16) char smem[16384];
  const int tid = threadIdx.x;
  const int wave = tid >> 6, lane = tid & 63;
  XCD_DECODE();
  const int wr = wave >> 1, wc = wave & 1;

  const int srow = lane >> 2, skb = (lane & 3) * 8;
  const int c0 = wave, c1 = wave + 4;
  const size_t ar0 = (size_t)(d0 + c0 * 16 + srow) * SEG + skb;
  const size_t ar1 = (size_t)(d0 + c1 * 16 + srow) * SEG + skb;
  const size_t br0 = ((size_t)b * TP + t0 + c0 * 16 + srow) * SEG + skb;
  const size_t br1 = ((size_t)b * TP + t0 + c1 * 16 + srow) * SEG + skb;

  f32x4 acc[4][4];
  #pragma unroll
  for (int i = 0; i < 4; ++i)
    #pragma unroll
    for (int j = 0; j < 4; ++j) acc[i][j] = (f32x4){0.f, 0.f, 0.f, 0.f};

  const int frow = (lane & 15) * 64, fk = (lane >> 4) * 16;

  for (int k0 = 0; k0 < SEG; k0 += 32) {
    GL16(A + ar0 + k0, 0    + c0 * 1024);
    GL16(A + ar1 + k0, 0    + c1 * 1024);
    GL16(B + br0 + k0, 8192 + c0 * 1024);
    GL16(B + br1 + k0, 8192 + c1 * 1024);
    __syncthreads();
    bf16x8 af[4], bf[4];
    #pragma unroll
    for (int f = 0; f < 4; ++f) {
      af[f] = *(const bf16x8*)(smem +        wr * 4096 + f * 1024 + frow + fk);
      bf[f] = *(const bf16x8*)(smem + 8192 + wc * 4096 + f * 1024 + frow + fk);
    }
    #pragma unroll
    for (int i = 0; i < 4; ++i)
      #pragma unroll
      for (int j = 0; j < 4; ++j)
        acc[i][j] = __builtin_amdgcn_mfma_f32_16x16x32_bf16(af[i], bf[j], acc[i][j], 0, 0, 0);
    __syncthreads();
  }

  const int orow = (lane >> 4) * 4, ocol = lane & 15;
  #pragma unroll
  for (int i = 0; i < 4; ++i) {
    int d = d0 + wr * 64 + i * 16 + orow;
    #pragma unroll
    for (int j = 0; j < 4; ++j) {
      int t = t0 + wc * 64 + j * 16 + ocol;
      ushort_t* p = N1 + ((size_t)b * NDIR + d) * TP + t;
      #pragma unroll
      for (int r = 0; r < 4; ++r) p[(size_t)r * TP] = f2b(acc[i][j][r]);
    }
  }
}

// ---------------------------------------------------------------- n2 GEMM + fused corr epilogue
// n2 = Hl.PR; corr = corr_un / sqrt(n1*n2 + 1e-8); atomic scatter by az.
__global__ __launch_bounds__(256, 3) void gemm_n2(
    const ushort_t* __restrict__ A, const ushort_t* __restrict__ B,
    const ushort_t* __restrict__ CU, const ushort_t* __restrict__ N1,
    const int* __restrict__ az, float* __restrict__ hrtf)
{
  __shared__ __align__(16) char smem[16384];
  const int tid = threadIdx.x;
  const int wave = tid >> 6, lane = tid & 63;
  XCD_DECODE();
  const int wr = wave >> 1, wc = wave & 1;

  const int srow = lane >> 2, skb = (lane & 3) * 8;
  const int c0 = wave, c1 = wave + 4;
  const size_t ar0 = (size_t)(d0 + c0 * 16 + srow) * SEG + skb;
  const size_t ar1 = (size_t)(d0 + c1 * 16 + srow) * SEG + skb;
  const size_t br0 = ((size_t)b * TP + t0 + c0 * 16 + srow) * SEG + skb;
  const size_t br1 = ((size_t)b * TP + t0 + c1 * 16 + srow) * SEG + skb;

  f32x4 acc[4][4];
  #pragma unroll
  for (int i = 0; i < 4; ++i)
    #pragma unroll
    for (int j = 0; j < 4; ++j) acc[i][j] = (f32x4){0.f, 0.f, 0.f, 0.f};

  const int frow = (lane & 15) * 64, fk = (lane >> 4) * 16;

  for (int k0 = 0; k0 < SEG; k0 += 32) {
    GL16(A + ar0 + k0, 0    + c0 * 1024);
    GL16(A + ar1 + k0, 0    + c1 * 1024);
    GL16(B + br0 + k0, 8192 + c0 * 1024);
    GL16(B + br1 + k0, 8192 + c1 * 1024);
    __syncthreads();
    bf16x8 af[4], bf[4];
    #pragma unroll
    for (int f = 0; f < 4; ++f) {
      af[f] = *(const bf16x8*)(smem +        wr * 4096 + f * 1024 + frow + fk);
      bf[f] = *(const bf16x8*)(smem + 8192 + wc * 4096 + f * 1024 + frow + fk);
    }
    #pragma unroll
    for (int i = 0; i < 4; ++i)
      #pragma unroll
      for (int j = 0; j < 4; ++j)
        acc[i][j] = __builtin_amdgcn_mfma_f32_16x16x32_bf16(af[i], bf[j], acc[i][j], 0, 0, 0);
    __syncthreads();
  }

  const int orow = (lane >> 4) * 4, ocol = lane & 15;
  #pragma unroll
  for (int i = 0; i < 4; ++i) {
    int dbase = d0 + wr * 64 + i * 16 + orow;
    #pragma unroll
    for (int j = 0; j < 4; ++j) {
      int t = t0 + wc * 64 + j * 16 + ocol;
      if (t < TFRAMES) {
        #pragma unroll
        for (int r = 0; r < 4; ++r) {
          int d = dbase + r;
          size_t off = ((size_t)b * NDIR + d) * TP + t;
          float n1v = b2f(N1[off]);
          float n2v = acc[i][j][r];
          float cu  = b2f(CU[off]);
          float cval = cu / sqrtf(n1v * n2v + 1e-8f);
          unsafeAtomicAdd(hrtf + ((size_t)b * NMELS + az[d]) * TFRAMES + t, cval);
        }
      }
    }
  }
}

// ---------------------------------------------------------------- mel GEMM + ch0..ch4 (fp32 acc)
__global__ __launch_bounds__(256) void mel_gemm(
    const float* __restrict__ MF,
    const ushort_t* __restrict__ PLh, const ushort_t* __restrict__ PRh,
    const ushort_t* __restrict__ FCh, const ushort_t* __restrict__ FCl,
    float* __restrict__ out)
{
  __shared__ float As[BKM][LDT];
  __shared__ float Bs[4][BKM][LDT];
  const int b  = blockIdx.y;
  const int t0 = blockIdx.x * 64;
  const int tid = threadIdx.x;
  const int tx = tid & 15, ty = tid >> 4;
  const int lr = tid >> 2, lk = (tid & 3) * 4;

  float aL[4][4] = {}, aR[4][4] = {}, aC[4][4] = {}, aI[4][4] = {};

  const size_t rb = (size_t)b * TP + t0 + lr;
  const ushort_t* Bp[4] = {PLh, PRh, FCh, FCh + SEG};
  const ushort_t* Bl[4] = {PLh, PRh, FCl, FCl + SEG};
  const size_t   Bst[4] = {SEG, SEG, K2, K2};

  for (int k0 = 0; k0 < SEG; k0 += BKM) {
    {
      float4 a = *(const float4*)(MF + (size_t)lr * SEG + k0 + lk);
      As[lk + 0][lr] = a.x; As[lk + 1][lr] = a.y;
      As[lk + 2][lr] = a.z; As[lk + 3][lr] = a.w;
    }
    #pragma unroll
    for (int m = 0; m < 4; ++m) {
      uint2 v = *(const uint2*)(Bp[m] + rb * Bst[m] + k0 + lk);
      float f0 = b2f(v.x & 0xffffu), f1 = b2f(v.x >> 16);
      float f2 = b2f(v.y & 0xffffu), f3 = b2f(v.y >> 16);
      if (m >= 2) {
        uint2 w = *(const uint2*)(Bl[m] + rb * Bst[m] + k0 + lk);
        f0 += b2f(w.x & 0xffffu); f1 += b2f(w.x >> 16);
        f2 += b2f(w.y & 0xffffu); f3 += b2f(w.y >> 16);
      }
      Bs[m][lk + 0][lr] = f0; Bs[m][lk + 1][lr] = f1;
      Bs[m][lk + 2][lr] = f2; Bs[m][lk + 3][lr] = f3;
    }
    __syncthreads();
    #pragma unroll
    for (int kk = 0; kk < BKM; ++kk) {
      float4 mf4 = *(const float4*)&As[kk][ty << 2];
      float4 pl4 = *(const float4*)&Bs[0][kk][tx << 2];
      float4 pr4 = *(const float4*)&Bs[1][kk][tx << 2];
      float4 cr4 = *(const float4*)&Bs[2][kk][tx << 2];
      float4 ci4 = *(const float4*)&Bs[3][kk][tx << 2];
      const float* mf = (const float*)&mf4;
      const float* pl = (const float*)&pl4; const float* pr = (const float*)&pr4;
      const float* cr = (const float*)&cr4; const float* ci = (const float*)&ci4;
      #pragma unroll
      for (int i = 0; i < 4; ++i)
        #pragma unroll
        for (int j = 0; j < 4; ++j) {
          aL[i][j] = fmaf(mf[i], pl[j], aL[i][j]);
          aR[i][j] = fmaf(mf[i], pr[j], aR[i][j]);
          aC[i][j] = fmaf(mf[i], cr[j], aC[i][j]);
          aI[i][j] = fmaf(mf[i], ci[j], aI[i][j]);
        }
    }
    __syncthreads();
  }

  #pragma unroll
  for (int i = 0; i < 4; ++i) {
    int m = (ty << 2) + i;
    #pragma unroll
    for (int j = 0; j < 4; ++j) {
      int t = t0 + (tx << 2) + j;
      if (t < TFRAMES) {
        float mlv = aL[i][j], mrv = aR[i][j], crv = aC[i][j], civ = aI[i][j];
        float ch0 = 10.0f * log10f(mlv + 1e-8f);
        float ch1 = 10.0f * log10f(mrv + 1e-8f);
        float ch2 = 10.0f * log10f(mlv / (mrv + 1e-8f) + 1e-8f);
        float nrm = sqrtf(crv * crv + civ * civ + 1e-8f);
        float ch3 = civ / nrm;
        float ch4 = crv / nrm;
        size_t bb = (size_t)b * 6 * NMELS;
        out[(bb + 0 * NMELS + m) * TFRAMES + t] = ch0;
        out[(bb + 1 * NMELS + m) * TFRAMES + t] = ch1;
        out[(bb + 2 * NMELS + m) * TFRAMES + t] = ch2;
        out[(bb + 3 * NMELS + m) * TFRAMES + t] = ch3;
        out[(bb + 4 * NMELS + m) * TFRAMES + t] = ch4;
      }
    }
  }
}

// ---------------------------------------------------------------- ch5 finalize
__global__ __launch_bounds__(256) void finalize_k(
    const float* __restrict__ hrtf, const int* __restrict__ az,
    float* __restrict__ out)
{
  __shared__ int red[256];
  const int m = blockIdx.x, b = blockIdx.y, tid = threadIdx.x;
  int c = 0;
  for (int j = tid; j < NDIR; j += 256) c += (az[j] == m) ? 1 : 0;
  red[tid] = c;
  __syncthreads();
  for (int st = 128; st > 0; st >>= 1) {
    if (tid < st) red[tid] += red[tid + st];
    __syncthreads();
  }
  float inv = 1.0f / ((float)red[0] + 1e-8f);
  const float* src = hrtf + ((size_t)b * NMELS + m) * TFRAMES;
  float* dst = out + (((size_t)b * 6 + 5) * NMELS + m) * TFRAMES;
  for (int t = tid; t < TFRAMES; t += 256) dst[t] = src[t] * inv;
}

// ---------------------------------------------------------------- launch
extern "C" void kernel_launch(void* const* d_in, const int* in_sizes, int n_in,
                              void* d_out, int out_size, void* d_ws, size_t ws_size,
                              hipStream_t stream) {
  const float* wave   = (const float*)d_in[0];
  const float* W_real = (const float*)d_in[1];
  const float* W_imag = (const float*)d_in[2];
  const float* Nhr    = (const float*)d_in[3];
  const float* Nhl    = (const float*)d_in[4];
  const int*   az     = (const int*)  d_in[5];
  const float* window = (const float*)d_in[6];
  const float* mel_fb = (const float*)d_in[7];
  float* out = (float*)d_out;

  float* fw      = (float*)d_ws;
  float* hrtf    = fw;
  float* MFp     = hrtf + N_HRTF;
  ushort_t* ub   = (ushort_t*)(MFp + N_MF);
  ushort_t* corr = ub;
  ushort_t* n1b  = corr + N_CORR;
  ushort_t* FCh  = n1b + N_CORR;
  ushort_t* FCl  = FCh + N_FC;
  ushort_t* PLh  = FCl + N_FC;
  ushort_t* PRh  = PLh + N_P;
  ushort_t* ACh  = PRh + N_P;
  ushort_t* AHrh = ACh + N_AC;
  ushort_t* AHlh = AHrh + N_AH;

  hipMemsetAsync(hrtf, 0, sizeof(float) * N_HRTF, stream);

  prep_k<<<2048, 256, 0, stream>>>(W_real, W_imag, Nhr, Nhl, mel_fb,
                                   ACh, AHrh, AHlh, MFp);

  stft_kernel<<<BATCH * TFRAMES, 256, 0, stream>>>(wave, window, PLh, PRh, FCh, FCl);

  gemm_c <<<NWG, 256, 0, stream>>>(ACh, FCh, corr);
  gemm_n1<<<NWG, 256, 0, stream>>>(AHrh, PLh, n1b);
  gemm_n2<<<NWG, 256, 0, stream>>>(AHlh, PRh, corr, n1b, az, hrtf);

  mel_gemm<<<dim3(16, BATCH), 256, 0, stream>>>(MFp, PLh, PRh, FCh, FCl, out);

  finalize_k<<<dim3(NMELS, BATCH), 256, 0, stream>>>(hrtf, az, out);
}